// Round 16
// baseline (146.159 us; speedup 1.0000x reference)
//
#include <hip/hip_runtime.h>
#include <hip/hip_bf16.h>

#define Nn 16384
#define Dd 256
#define L2E 1.4426950408889634f
#define LN2 0.6931471805599453f

typedef __attribute__((ext_vector_type(8))) int int8v;
typedef __attribute__((ext_vector_type(16))) float f32x16;
typedef __attribute__((ext_vector_type(2))) float f32x2;

__device__ inline void gload_lds16(const void* g, void* l) {
    __builtin_amdgcn_global_load_lds(
        (const __attribute__((address_space(1))) void*)g,
        (__attribute__((address_space(3))) void*)l, 16, 0, 0);
}

// fp32 -> fp8 e4m3 (HW RNE). A pre-scaled by log2e: epilogue softplus works in
// exp2/log2 domain with no per-element muls.
__global__ __launch_bounds__(256) void cvt_kernel(
        const float4* __restrict__ a, const float4* __restrict__ b,
        int2* __restrict__ oa, int2* __restrict__ ob) {
    int i = blockIdx.x * 256 + threadIdx.x;
    float4 a0 = a[2 * i], a1 = a[2 * i + 1];
    float4 b0 = b[2 * i], b1 = b[2 * i + 1];
    int alo = __builtin_amdgcn_cvt_pk_fp8_f32(a0.x * L2E, a0.y * L2E, 0, false);
    alo     = __builtin_amdgcn_cvt_pk_fp8_f32(a0.z * L2E, a0.w * L2E, alo, true);
    int ahi = __builtin_amdgcn_cvt_pk_fp8_f32(a1.x * L2E, a1.y * L2E, 0, false);
    ahi     = __builtin_amdgcn_cvt_pk_fp8_f32(a1.z * L2E, a1.w * L2E, ahi, true);
    int blo = __builtin_amdgcn_cvt_pk_fp8_f32(b0.x, b0.y, 0, false);
    blo     = __builtin_amdgcn_cvt_pk_fp8_f32(b0.z, b0.w, blo, true);
    int bhi = __builtin_amdgcn_cvt_pk_fp8_f32(b1.x, b1.y, 0, false);
    bhi     = __builtin_amdgcn_cvt_pk_fp8_f32(b1.z, b1.w, bhi, true);
    oa[i] = make_int2(alo, ahi);
    ob[i] = make_int2(blo, bhi);
}

// 2x ds_read_b128 of one lane's 32 contiguous K-bytes from a [rows][256B]
// full-K LDS tile, XOR-deswizzled (16 chunks/row, chunk ^= row&15).
// Measured ZERO bank conflicts (R8-R15).
__device__ inline int8v read_frag256(const unsigned char* base, int rr, int cb) {
    int x = rr & 15;
    int4 lo = *(const int4*)&base[rr * 256 + ((cb ^ x) * 16)];
    int4 hi = *(const int4*)&base[rr * 256 + (((cb + 1) ^ x) * 16)];
    int8v r;
    r[0] = lo.x; r[1] = lo.y; r[2] = lo.z; r[3] = lo.w;
    r[4] = hi.x; r[5] = hi.y; r[6] = hi.z; r[7] = hi.w;
    return r;
}

// Fused MX-fp8 GEMM (sim' = log2e * za.zb^T, unit e8m0 scales) + siglip loss.
// R15 structure re-partitioned for SIMD-level latency hiding: same 256x128
// tile, same full-K 96KB staged-once LDS (zero-conflict XOR-16), same math —
// but 1024 thr = 16 waves (4M x 4N), wave tile 64x32 -> acc[2][1] f32x16
// (32 AGPR; arch ~85 -> ~120 unified/wave x 4 waves/SIMD = 480 < 512 pool).
// 4 waves/SIMD interleave MFMA, ds_read and epilogue VALU (R15 had only 2).
__global__ __launch_bounds__(1024, 1) void siglip_kernel(
        const unsigned char* __restrict__ ga,   // za*log2e fp8 [16384][256]
        const unsigned char* __restrict__ gb,   // zb fp8 [16384][256]
        const float* __restrict__ bp,           // bias scalar
        float* __restrict__ out) {
    __shared__ unsigned char As[256 * 256];   // 64 KB, full-K A tile
    __shared__ unsigned char Bs[128 * 256];   // 32 KB, full-K B tile
    __shared__ float wsum[16];

    const int tid  = threadIdx.x;
    const int lane = tid & 63;
    const int wid  = tid >> 6;     // 0..15
    const int wm   = wid >> 2;     // 0..3 -> 64-row slice of the 256-row tile
    const int wn   = wid & 3;      // 0..3 -> 32-col slice of the 128-col tile
    const int l31  = lane & 31;
    const int h    = lane >> 5;

    // XCD-chunked swizzle + 8x8 supertile (grid 8192 = 8 XCD x 1024).
    const int bid = blockIdx.x;
    const int nid = (bid & 7) * 1024 + (bid >> 3);
    const int sc  = nid >> 6, sl = nid & 63;
    const int by  = (sc & 7) * 8 + (sl >> 3);    // 0..63  (M/256)
    const int bx  = (sc >> 3) * 8 + (sl & 7);    // 0..127 (N/128)
    const size_t rowA0 = (size_t)by * 256;
    const size_t rowB0 = (size_t)bx * 128;

    const float b2 = bp[0] * L2E;

    // ---- stage the whole block slice ONCE: 6 loads/thread ----
    // source chunk pre-swizzled ((c&15)^(row&15)) so read_frag256's XOR'd
    // ds_read_b128 deswizzles correctly (bank-conflict-free, proven).
#pragma unroll
    for (int p = 0; p < 4; ++p) {
        int c = p * 1024 + tid; int row = c >> 4;
        int scl = (c & 15) ^ (row & 15);
        gload_lds16(&ga[(rowA0 + row) * Dd + scl * 16], &As[c * 16]);
    }
#pragma unroll
    for (int p = 0; p < 2; ++p) {
        int c = p * 1024 + tid; int row = c >> 4;
        int scl = (c & 15) ^ (row & 15);
        gload_lds16(&gb[(rowB0 + row) * Dd + scl * 16], &Bs[c * 16]);
    }

    // bias folded into MFMA C operand: acc ends as y = s' - b2
    f32x16 acc[2];
#pragma unroll
    for (int mf = 0; mf < 2; ++mf)
#pragma unroll
        for (int q = 0; q < 16; ++q) acc[mf][q] = -b2;

    asm volatile("s_waitcnt vmcnt(0)" ::: "memory");
    __builtin_amdgcn_s_barrier();
    asm volatile("" ::: "memory");

    // ---- K = 256 in 4 s-steps of 64B, straight-line, 8 MFMAs/wave ----
#pragma unroll
    for (int s = 0; s < 4; ++s) {
        int cb = s * 4 + h * 2;
        int8v aF0 = read_frag256(As, wm * 64 + l31, cb);
        int8v aF1 = read_frag256(As, wm * 64 + 32 + l31, cb);
        int8v bF0 = read_frag256(Bs, wn * 32 + l31, cb);
        acc[0] = __builtin_amdgcn_mfma_scale_f32_32x32x64_f8f6f4(
            aF0, bF0, acc[0], 0, 0, 0, 0x7F7F7F7F, 0, 0x7F7F7F7F);
        acc[1] = __builtin_amdgcn_mfma_scale_f32_32x32x64_f8f6f4(
            aF1, bF0, acc[1], 0, 0, 0, 0x7F7F7F7F, 0, 0x7F7F7F7F);
    }
    // no trailing barrier: waves desync into the VALU/trans epilogue.

    // ---- epilogue (packed): nats/elem = ln2*max(y,0) + 2^-|y|
    //   Σmax(y,0) = 0.5*(Σy + Σ|y|) -> three pk_add-able running sums.
    f32x2 sy = {0.f, 0.f}, sa = {0.f, 0.f}, se = {0.f, 0.f};
#pragma unroll
    for (int mf = 0; mf < 2; ++mf)
#pragma unroll
        for (int q = 0; q < 16; q += 2) {
            float y0 = acc[mf][q];
            float y1 = acc[mf][q + 1];
            f32x2 yv = {y0, y1};
            f32x2 av = {fabsf(y0), fabsf(y1)};
            sy += yv;                   // v_pk_add_f32
            sa += av;                   // v_pk_add_f32
            f32x2 ev = {__builtin_amdgcn_exp2f(-av[0]),
                        __builtin_amdgcn_exp2f(-av[1])};
            se += ev;                   // v_pk_add_f32
        }
    float ld = 0.f;

    // Diagonal correction where this block's row-range meets its col-range.
    if ((bx >> 1) == by) {
#pragma unroll
        for (int mf = 0; mf < 2; ++mf)
#pragma unroll
            for (int q = 0; q < 16; ++q) {
                int i_loc = wm * 64 + mf * 32 + (q & 3) + 8 * (q >> 2) + 4 * h;
                int j_loc = (bx & 1) * 128 + wn * 32 + l31;
                if (i_loc == j_loc) {
                    float y  = acc[mf][q];
                    float u  = -(y + 2.f * b2);
                    float ey = __builtin_amdgcn_exp2f(-fabsf(y));
                    float eu = __builtin_amdgcn_exp2f(-fabsf(u));
                    float off = LN2 * fmaxf(y, 0.f) + ey;
                    float dg  = LN2 * fmaxf(u, 0.f) + eu;
                    ld += dg - off;
                }
            }
    }

    // v = ln2 * 0.5*(Σy + Σ|y|) + Σe + diag
    float v = fmaf(LN2 * 0.5f, (sy[0] + sy[1]) + (sa[0] + sa[1]),
                   (se[0] + se[1]) + ld);

    // wave reduce then block reduce
#pragma unroll
    for (int off = 32; off; off >>= 1)
        v += __shfl_down(v, off);
    if (lane == 0) wsum[wid] = v;
    __syncthreads();
    if (tid == 0) {
        float t = 0.f;
#pragma unroll
        for (int w = 0; w < 16; ++w) t += wsum[w];
        atomicAdd(out, t * (1.0f / ((float)Nn * (float)Nn)));
    }
}

extern "C" void kernel_launch(void* const* d_in, const int* in_sizes, int n_in,
                              void* d_out, int out_size, void* d_ws, size_t ws_size,
                              hipStream_t stream) {
    const float* za   = (const float*)d_in[0];
    const float* zb   = (const float*)d_in[1];
    const float* bias = (const float*)d_in[2];

    unsigned char* wa = (unsigned char*)d_ws;
    unsigned char* wb = wa + (size_t)Nn * Dd;

    // zero the output accumulator (harness does not re-poison between replays)
    hipMemsetAsync(d_out, 0, sizeof(float), stream);

    // fp32 -> fp8 pre-pass (A pre-scaled by log2e)
    cvt_kernel<<<dim3(Nn * Dd / 2048), 256, 0, stream>>>(
        (const float4*)za, (const float4*)zb, (int2*)wa, (int2*)wb);

    // fused GEMM + loss: grid 64 x 128 = 8192 blocks
    siglip_kernel<<<dim3(8192), 1024, 0, stream>>>(wa, wb, bias, (float*)d_out);
}

// Round 18
// 130.131 us; speedup vs baseline: 1.1232x; 1.1232x over previous
//
#include <hip/hip_runtime.h>
#include <hip/hip_bf16.h>

#define Nn 16384
#define Dd 256
#define L2E 1.4426950408889634f
#define LN2 0.6931471805599453f

typedef __attribute__((ext_vector_type(8))) int int8v;
typedef __attribute__((ext_vector_type(16))) float f32x16;
typedef __attribute__((ext_vector_type(2))) float f32x2;

__device__ inline void gload_lds16(const void* g, void* l) {
    __builtin_amdgcn_global_load_lds(
        (const __attribute__((address_space(1))) void*)g,
        (__attribute__((address_space(3))) void*)l, 16, 0, 0);
}

// fp32 -> fp8 e4m3 (HW RNE). A pre-scaled by log2e: epilogue softplus works in
// exp2/log2 domain with no per-element muls.
__global__ __launch_bounds__(256) void cvt_kernel(
        const float4* __restrict__ a, const float4* __restrict__ b,
        int2* __restrict__ oa, int2* __restrict__ ob) {
    int i = blockIdx.x * 256 + threadIdx.x;
    float4 a0 = a[2 * i], a1 = a[2 * i + 1];
    float4 b0 = b[2 * i], b1 = b[2 * i + 1];
    int alo = __builtin_amdgcn_cvt_pk_fp8_f32(a0.x * L2E, a0.y * L2E, 0, false);
    alo     = __builtin_amdgcn_cvt_pk_fp8_f32(a0.z * L2E, a0.w * L2E, alo, true);
    int ahi = __builtin_amdgcn_cvt_pk_fp8_f32(a1.x * L2E, a1.y * L2E, 0, false);
    ahi     = __builtin_amdgcn_cvt_pk_fp8_f32(a1.z * L2E, a1.w * L2E, ahi, true);
    int blo = __builtin_amdgcn_cvt_pk_fp8_f32(b0.x, b0.y, 0, false);
    blo     = __builtin_amdgcn_cvt_pk_fp8_f32(b0.z, b0.w, blo, true);
    int bhi = __builtin_amdgcn_cvt_pk_fp8_f32(b1.x, b1.y, 0, false);
    bhi     = __builtin_amdgcn_cvt_pk_fp8_f32(b1.z, b1.w, bhi, true);
    oa[i] = make_int2(alo, ahi);
    ob[i] = make_int2(blo, bhi);
}

// 2x ds_read_b128 of one lane's 32 contiguous K-bytes from a [rows][256B]
// full-K LDS tile, XOR-deswizzled (16 chunks/row, chunk ^= row&15).
// Measured ZERO bank conflicts (R8-R16). LDS dest is LINEAR (rule #21):
// swizzle lives on the global SOURCE side only.
__device__ inline int8v read_frag256(const unsigned char* base, int rr, int cb) {
    int x = rr & 15;
    int4 lo = *(const int4*)&base[rr * 256 + ((cb ^ x) * 16)];
    int4 hi = *(const int4*)&base[rr * 256 + (((cb + 1) ^ x) * 16)];
    int8v r;
    r[0] = lo.x; r[1] = lo.y; r[2] = lo.z; r[3] = lo.w;
    r[4] = hi.x; r[5] = hi.y; r[6] = hi.z; r[7] = hi.w;
    return r;
}

// Fused MX-fp8 GEMM (sim' = log2e * za.zb^T, unit e8m0 scales) + siglip loss.
// Persistent-A pipelined-B (R8/R9 structure — correct both times) made
// register-feasible by 256-THREAD blocks: 4 waves = 1 wave/SIMD ->
// __launch_bounds__(256,1) caps at 512 unified regs/wave (512-thr blocks
// hard-cap at 256, which is why every looped variant spilled). Wave tile
// 64x128 -> acc[2][4] f32x16 = 128 AGPR; even 2 pipelined generations fit.
// Block = 256 M-rows x 1024 N-cols (8 panels of 128). A[256][256B] staged
// once (64KB); B double-buffered (2x32KB), 2 panels ahead, counted vmcnt(8)
// only (vmcnt(0) once, at the last panel). Per-panel packed epilogue sits
// between stage-issue and the wait -> overlaps B-flight.
__global__ __launch_bounds__(256, 1) void siglip_kernel(
        const unsigned char* __restrict__ ga,   // za*log2e fp8 [16384][256]
        const unsigned char* __restrict__ gb,   // zb fp8 [16384][256]
        const float* __restrict__ bp,           // bias scalar
        float* __restrict__ out) {
    __shared__ unsigned char As[256 * 256];    // 64 KB, full-K A tile
    __shared__ unsigned char Bs0[128 * 256];   // 32 KB, B panel buffer 0
    __shared__ unsigned char Bs1[128 * 256];   // 32 KB, B panel buffer 1
    __shared__ float wsum[4];

    const int tid  = threadIdx.x;
    const int lane = tid & 63;
    const int wid  = tid >> 6;     // 0..3
    const int wm   = wid;          // 64-row slice of the 256-row tile
    const int l31  = lane & 31;
    const int h    = lane >> 5;

    // XCD-chunked bijective swizzle (grid 1024 = 8 XCD x 128); consecutive
    // nid share the A panel (same by) and sweep B -> per-XCD L2 locality.
    const int bid = blockIdx.x;
    const int nid = (bid & 7) * 128 + (bid >> 3);
    const int by  = nid >> 4;      // 0..63  M-tile (256 rows)
    const int bxs = nid & 15;      // 0..15  N-supertile (1024 cols)
    const size_t rowA0 = (size_t)by * 256;
    const int    rB0   = bxs * 1024;

    const float b2 = bp[0] * L2E;

    // ---- stage A once: 16 loads/thread; LDS dest linear, source swizzled ----
#pragma unroll
    for (int p = 0; p < 16; ++p) {
        int c = p * 256 + tid; int row = c >> 4;
        int scl = (c & 15) ^ (row & 15);
        gload_lds16(&ga[(rowA0 + row) * Dd + scl * 16], &As[c * 16]);
    }

#define STAGE_B(DST, T)                                                       \
    {                                                                         \
        _Pragma("unroll")                                                     \
        for (int p = 0; p < 8; ++p) {                                         \
            int c = p * 256 + tid; int row = c >> 4;                          \
            int scl = (c & 15) ^ (row & 15);                                  \
            gload_lds16(&gb[(size_t)(rB0 + (T) * 128 + row) * Dd + scl * 16], \
                        &(DST)[c * 16]);                                      \
        }                                                                     \
    }

    STAGE_B(Bs0, 0)
    STAGE_B(Bs1, 1)

    // outstanding: A(16)+B0(8)+B1(8)=32; wait to <=8 -> A and B0 landed.
    asm volatile("s_waitcnt vmcnt(8)" ::: "memory");
    __builtin_amdgcn_s_barrier();
    asm volatile("" ::: "memory");

    f32x2 sy = {0.f, 0.f}, sa = {0.f, 0.f}, se = {0.f, 0.f};
    float ld = 0.f;
    const int diagblk = (bxs == (by >> 2));
    const int dtile   = (by & 3);

#pragma unroll 1
    for (int t = 0; t < 8; ++t) {
        const unsigned char* Bb = (t & 1) ? Bs1 : Bs0;
        unsigned char*       Bw = (t & 1) ? Bs1 : Bs0;

        f32x16 acc[2][4];
#pragma unroll
        for (int mf = 0; mf < 2; ++mf)
#pragma unroll
            for (int nf = 0; nf < 4; ++nf)
#pragma unroll
                for (int q = 0; q < 16; ++q) acc[mf][nf][q] = -b2;

        // ---- 4 s-steps of K=64B: 12 ds_reads + 8 MFMAs each ----
#pragma unroll
        for (int s = 0; s < 4; ++s) {
            int cb = s * 4 + h * 2;
            int8v aF0 = read_frag256(As, wm * 64 + l31, cb);
            int8v aF1 = read_frag256(As, wm * 64 + 32 + l31, cb);
#pragma unroll
            for (int nf = 0; nf < 4; ++nf) {
                int8v bF = read_frag256(Bb, nf * 32 + l31, cb);
                acc[0][nf] = __builtin_amdgcn_mfma_scale_f32_32x32x64_f8f6f4(
                    aF0, bF, acc[0][nf], 0, 0, 0, 0x7F7F7F7F, 0, 0x7F7F7F7F);
                acc[1][nf] = __builtin_amdgcn_mfma_scale_f32_32x32x64_f8f6f4(
                    aF1, bF, acc[1][nf], 0, 0, 0, 0x7F7F7F7F, 0, 0x7F7F7F7F);
            }
        }

        // all waves done reading this buffer -> safe to re-stage it
        asm volatile("" ::: "memory");
        __builtin_amdgcn_s_barrier();
        asm volatile("" ::: "memory");
        if (t < 6) STAGE_B(Bw, t + 2)

        // ---- per-panel epilogue (packed; overlaps B-flight) ----
        // nats/elem = ln2*max(y,0) + 2^-|y|; Σmax = 0.5*(Σy+Σ|y|)
#pragma unroll
        for (int mf = 0; mf < 2; ++mf)
#pragma unroll
            for (int nf = 0; nf < 4; ++nf)
#pragma unroll
                for (int q = 0; q < 16; q += 2) {
                    float y0 = acc[mf][nf][q];
                    float y1 = acc[mf][nf][q + 1];
                    f32x2 yv = {y0, y1};
                    f32x2 av = {fabsf(y0), fabsf(y1)};
                    sy += yv;
                    sa += av;
                    f32x2 ev = {__builtin_amdgcn_exp2f(-av[0]),
                                __builtin_amdgcn_exp2f(-av[1])};
                    se += ev;
                }

        // diagonal correction: only on the 2 panels meeting this row-range
        if (diagblk && (t >> 1) == dtile) {
#pragma unroll
            for (int mf = 0; mf < 2; ++mf)
#pragma unroll
                for (int nf = 0; nf < 4; ++nf)
#pragma unroll
                    for (int q = 0; q < 16; ++q) {
                        int i_loc = wm * 64 + mf * 32 + (q & 3) + 8 * (q >> 2) + 4 * h;
                        int jg    = ((t & 1) << 7) + nf * 32 + l31;
                        if (i_loc == jg) {
                            float y  = acc[mf][nf][q];
                            float u  = -(y + 2.f * b2);
                            float ey = __builtin_amdgcn_exp2f(-fabsf(y));
                            float eu = __builtin_amdgcn_exp2f(-fabsf(u));
                            float off = LN2 * fmaxf(y, 0.f) + ey;
                            float dg  = LN2 * fmaxf(u, 0.f) + eu;
                            ld += dg - off;
                        }
                    }
        }

        if (t < 6) {
            asm volatile("s_waitcnt vmcnt(8)" ::: "memory");  // B(t+1) landed
            __builtin_amdgcn_s_barrier();
            asm volatile("" ::: "memory");
        } else if (t == 6) {
            asm volatile("s_waitcnt vmcnt(0)" ::: "memory");  // B7 landed
            __builtin_amdgcn_s_barrier();
            asm volatile("" ::: "memory");
        }
    }

    // v = ln2 * 0.5*(Σy + Σ|y|) + Σe + diag
    float v = fmaf(LN2 * 0.5f, (sy[0] + sy[1]) + (sa[0] + sa[1]),
                   (se[0] + se[1]) + ld);

    // wave reduce then block reduce
#pragma unroll
    for (int off = 32; off; off >>= 1)
        v += __shfl_down(v, off);
    if (lane == 0) wsum[wid] = v;
    __syncthreads();
    if (tid == 0) {
        float t = wsum[0] + wsum[1] + wsum[2] + wsum[3];
        atomicAdd(out, t * (1.0f / ((float)Nn * (float)Nn)));
    }
#undef STAGE_B
}

extern "C" void kernel_launch(void* const* d_in, const int* in_sizes, int n_in,
                              void* d_out, int out_size, void* d_ws, size_t ws_size,
                              hipStream_t stream) {
    const float* za   = (const float*)d_in[0];
    const float* zb   = (const float*)d_in[1];
    const float* bias = (const float*)d_in[2];

    unsigned char* wa = (unsigned char*)d_ws;
    unsigned char* wb = wa + (size_t)Nn * Dd;

    // zero the output accumulator (harness does not re-poison between replays)
    hipMemsetAsync(d_out, 0, sizeof(float), stream);

    // fp32 -> fp8 pre-pass (A pre-scaled by log2e)
    cvt_kernel<<<dim3(Nn * Dd / 2048), 256, 0, stream>>>(
        (const float4*)za, (const float4*)zb, (int2*)wa, (int2*)wb);

    // fused GEMM + loss: 64 M-tiles x 16 N-supertiles = 1024 blocks, 256 thr
    siglip_kernel<<<dim3(1024), 256, 0, stream>>>(wa, wb, bias, (float*)d_out);
}